// Round 7
// baseline (678.041 us; speedup 1.0000x reference)
//
#include <hip/hip_runtime.h>
#include <hip/hip_bf16.h>
#include <math.h>

// Problem constants (reference: B=64, L=1024, H=64, VOCAB=64)
#define BB 64
#define LL 1024
#define HH 64

typedef float v4f __attribute__((ext_vector_type(4)));
#define FMA4(a, b, c) __builtin_elementwise_fma((a), (b), (c))

// ---------------------------------------------------------------------------
// Kernel 1: per-token phase (unchanged from R6 -- passing).
// block = 256 threads (4 waves), 32 tokens/block, grid = 2048.
// Writes packed stream knv[b][t] = [kn(64) | v(64)] and vthr[b][t] =
// 0.4*sqrt(vn2)  (EXACT R2/R3 gate numerics).
// ---------------------------------------------------------------------------
__global__ __launch_bounds__(256, 1)
void token_kernel(const int* __restrict__ seq,
                  const float* __restrict__ embed_W,
                  const float* __restrict__ ff_W1, const float* __restrict__ ff_b1,
                  const float* __restrict__ ff_W2, const float* __restrict__ ff_b2,
                  const float* __restrict__ ln_g, const float* __restrict__ ln_b,
                  const float* __restrict__ kp_W, const float* __restrict__ vp_W,
                  const float* __restrict__ qp_W,
                  float* __restrict__ knv, float* __restrict__ vthr,
                  float* __restrict__ qbuf)
{
    __shared__ __align__(16) float h_s[32][64];    // 8 KB
    __shared__ __align__(16) float t1_s[32][128];  // 16 KB
    __shared__ __align__(16) float hn_s[32][64];   // 8 KB

    const int tid  = threadIdx.x;
    const int tok0 = blockIdx.x * 32;

    // ---- Stage A: embedding gather into LDS ----
#pragma unroll
    for (int k = 0; k < 8; ++k) {
        int e   = k * 256 + tid;
        int tok = e >> 6, i = e & 63;
        int s   = seq[tok0 + tok];
        h_s[tok][i] = embed_W[s * 64 + i];
    }
    __syncthreads();

    // ---- Stage B: FF1 (64 -> 128, ReLU), packed ----
    {
        const int j = tid & 127;
        const int g = tid >> 7;
        v4f w1v[16];
#pragma unroll
        for (int w = 0; w < 16; ++w) {
            w1v[w].x = ff_W1[(4*w+0) * 128 + j];
            w1v[w].y = ff_W1[(4*w+1) * 128 + j];
            w1v[w].z = ff_W1[(4*w+2) * 128 + j];
            w1v[w].w = ff_W1[(4*w+3) * 128 + j];
        }
        const float b1j = ff_b1[j];
#pragma unroll
        for (int tk = 0; tk < 16; ++tk) {
            const int tok = g * 16 + tk;
            const v4f* h4 = (const v4f*)h_s[tok];
            v4f acc = {b1j, 0.f, 0.f, 0.f};
#pragma unroll
            for (int w = 0; w < 16; ++w) acc = FMA4(h4[w], w1v[w], acc);
            t1_s[tok][j] = fmaxf((acc.x + acc.y) + (acc.z + acc.w), 0.f);
        }
    }
    __syncthreads();

    // ---- Stage C: FF2 (128 -> 64) + residual + LayerNorm, packed ----
    {
        const int i  = tid & 63;
        const int w4 = tid >> 6;
        const float b2i = ff_b2[i];
        const float gi  = ln_g[i];
        const float bi  = ln_b[i];
        float accf[8];
#pragma unroll
        for (int tk = 0; tk < 8; ++tk) accf[tk] = b2i;
#pragma unroll
        for (int h = 0; h < 2; ++h) {
            v4f w2v[16];
#pragma unroll
            for (int w = 0; w < 16; ++w) {
                w2v[w].x = ff_W2[(h*64 + 4*w+0) * 64 + i];
                w2v[w].y = ff_W2[(h*64 + 4*w+1) * 64 + i];
                w2v[w].z = ff_W2[(h*64 + 4*w+2) * 64 + i];
                w2v[w].w = ff_W2[(h*64 + 4*w+3) * 64 + i];
            }
#pragma unroll
            for (int tk = 0; tk < 8; ++tk) {
                const int tok = w4 * 8 + tk;
                const v4f* t4 = (const v4f*)&t1_s[tok][h*64];
                v4f acc = {0.f, 0.f, 0.f, 0.f};
#pragma unroll
                for (int w = 0; w < 16; ++w) acc = FMA4(t4[w], w2v[w], acc);
                accf[tk] += (acc.x + acc.y) + (acc.z + acc.w);
            }
        }
#pragma unroll
        for (int tk = 0; tk < 8; ++tk) {
            const int tok = w4 * 8 + tk;
            float x = h_s[tok][i] + accf[tk];
            float s = x;
#pragma unroll
            for (int m = 32; m > 0; m >>= 1) s += __shfl_xor(s, m);
            float mu = s * (1.f / 64.f);
            float d  = x - mu;
            float s2 = d * d;
#pragma unroll
            for (int m = 32; m > 0; m >>= 1) s2 += __shfl_xor(s2, m);
            float var = s2 * (1.f / 64.f);
            hn_s[tok][i] = d / sqrtf(var + 1e-5f) * gi + bi;
        }
    }
    __syncthreads();

    // ---- Stage D: kn/v packed stream (t<1023) OR q (t==1023) ----
    {
        const int i  = tid & 63;
        const int w4 = tid >> 6;
        v4f kcv[16], vcv[16];
#pragma unroll
        for (int w = 0; w < 16; ++w) {
            kcv[w].x = kp_W[(4*w+0) * 64 + i]; kcv[w].y = kp_W[(4*w+1) * 64 + i];
            kcv[w].z = kp_W[(4*w+2) * 64 + i]; kcv[w].w = kp_W[(4*w+3) * 64 + i];
            vcv[w].x = vp_W[(4*w+0) * 64 + i]; vcv[w].y = vp_W[(4*w+1) * 64 + i];
            vcv[w].z = vp_W[(4*w+2) * 64 + i]; vcv[w].w = vp_W[(4*w+3) * 64 + i];
        }
#pragma unroll
        for (int tk = 0; tk < 8; ++tk) {
            const int tok = w4 * 8 + tk;
            const int tg  = tok0 + tok;
            const int b   = tg >> 10;
            const int t   = tg & 1023;
            const v4f* hn4 = (const v4f*)hn_s[tok];
            if (t < 1023) {
                v4f ka = {0.f,0.f,0.f,0.f}, va = {0.f,0.f,0.f,0.f};
#pragma unroll
                for (int w = 0; w < 16; ++w) {
                    v4f hv = hn4[w];
                    ka = FMA4(hv, kcv[w], ka);
                    va = FMA4(hv, vcv[w], va);
                }
                float kas = (ka.x + ka.y) + (ka.z + ka.w);
                float vas = (va.x + va.y) + (va.z + va.w);
                float kn2 = kas * kas, vn2 = vas * vas;
#pragma unroll
                for (int m = 32; m > 0; m >>= 1) {
                    kn2 += __shfl_xor(kn2, m);
                    vn2 += __shfl_xor(vn2, m);
                }
                float knorm = fmaxf(sqrtf(kn2), 1e-12f);
                size_t row = ((size_t)b * 1024 + t) * 128;
                knv[row + i]      = kas / knorm;
                knv[row + 64 + i] = vas;
                if (i == 0) vthr[b * 1024 + t] = 0.4f * sqrtf(vn2);
            } else {
                v4f qa = {0.f,0.f,0.f,0.f};
#pragma unroll
                for (int w = 0; w < 16; ++w) {
                    v4f qw;
                    qw.x = qp_W[(4*w+0)*64 + i]; qw.y = qp_W[(4*w+1)*64 + i];
                    qw.z = qp_W[(4*w+2)*64 + i]; qw.w = qp_W[(4*w+3)*64 + i];
                    qa = FMA4(hn4[w], qw, qa);
                }
                qbuf[b * 64 + i] = (qa.x + qa.y) + (qa.z + qa.w);
            }
        }
    }
}

// ---------------------------------------------------------------------------
// Kernel 2: sequential fast-weight scan + output head -- SCALAR-PATH REWRITE.
// One wave per batch. Lane i owns M row i (16 v4f = 64 VGPRs).
// R2/R3/R6 all plateaued at 775-885 cyc/step because kn reached the lanes via
// ~18 broadcast ds_read ops/step (~40 cyc each through the LDS return
// crossbar), and register double-buffering spilled (VGPR cap). Fix: kn and th
// are WAVE-UNIFORM -> load via uniform addresses from __restrict const
// pointers (kernel stores only to `out` -> noclobber) so the compiler selects
// s_load into SGPRs: separate register file, separate pipe, zero VGPR
// pressure, FMAs read the SGPR operand directly. Only v (per-lane) remains a
// coalesced vector load, 1-step lookahead. No LDS staging, no DMA, no asm.
// FMA tree / DPP reduce / gate compare are byte-for-byte R6 -> bit-identical.
// ---------------------------------------------------------------------------

template<int CTRL>
__device__ __forceinline__ float dppadd(float x) {
    int y = __builtin_amdgcn_update_dpp(0, __float_as_int(x), CTRL, 0xF, 0xF, true);
    return x + __int_as_float(y);
}

__global__ __launch_bounds__(64, 1)
void scan_kernel(const float* __restrict__ knv,
                 const float* __restrict__ vthr,
                 const float* __restrict__ qbuf,
                 const float* __restrict__ rp_W, const float* __restrict__ rp_b,
                 const float* __restrict__ out_W, const float* __restrict__ out_b,
                 float* __restrict__ out)
{
    const int b    = blockIdx.x;
    const int lane = threadIdx.x;
    const float* __restrict__ knvb = knv  + (size_t)b * 1024 * 128;
    const float* __restrict__ thrb = vthr + (size_t)b * 1024;

    __shared__ float sh[64];

    v4f m0={0,0,0,0},m1={0,0,0,0},m2={0,0,0,0},m3={0,0,0,0},
        m4={0,0,0,0},m5={0,0,0,0},m6={0,0,0,0},m7={0,0,0,0},
        m8={0,0,0,0},m9={0,0,0,0},m10={0,0,0,0},m11={0,0,0,0},
        m12={0,0,0,0},m13={0,0,0,0},m14={0,0,0,0},m15={0,0,0,0};

    // per-lane v and uniform threshold, 1-step lookahead
    float vv = knvb[64 + lane];
    float th = thrb[0];

#pragma unroll 1
    for (int t = 0; t < 1023; ++t) {
        // ---- kn row for step t: 64 wave-uniform loads -> SGPRs (s_load) ----
        const float* __restrict__ kp = knvb + (size_t)t * 128;
        v4f k0  = {kp[0],  kp[1],  kp[2],  kp[3]};
        v4f k1  = {kp[4],  kp[5],  kp[6],  kp[7]};
        v4f k2  = {kp[8],  kp[9],  kp[10], kp[11]};
        v4f k3  = {kp[12], kp[13], kp[14], kp[15]};
        v4f k4  = {kp[16], kp[17], kp[18], kp[19]};
        v4f k5  = {kp[20], kp[21], kp[22], kp[23]};
        v4f k6  = {kp[24], kp[25], kp[26], kp[27]};
        v4f k7  = {kp[28], kp[29], kp[30], kp[31]};
        v4f k8  = {kp[32], kp[33], kp[34], kp[35]};
        v4f k9  = {kp[36], kp[37], kp[38], kp[39]};
        v4f k10 = {kp[40], kp[41], kp[42], kp[43]};
        v4f k11 = {kp[44], kp[45], kp[46], kp[47]};
        v4f k12 = {kp[48], kp[49], kp[50], kp[51]};
        v4f k13 = {kp[52], kp[53], kp[54], kp[55]};
        v4f k14 = {kp[56], kp[57], kp[58], kp[59]};
        v4f k15 = {kp[60], kp[61], kp[62], kp[63]};

        // ---- next step's v (per-lane vector load) + th (uniform) ----
        // t=1022 reads row 1023 / thr[1023]: in-bounds, value discarded.
        float vn  = knvb[(size_t)(t + 1) * 128 + 64 + lane];
        float thn = thrb[t + 1];

        // ---- step: dot -> err reduce -> gate -> rank-1 update (R6 tree) ----
        v4f a0_ = FMA4(m0, k0, FMA4(m4, k4, FMA4(m8,  k8,  m12 * k12)));
        v4f a1_ = FMA4(m1, k1, FMA4(m5, k5, FMA4(m9,  k9,  m13 * k13)));
        v4f a2_ = FMA4(m2, k2, FMA4(m6, k6, FMA4(m10, k10, m14 * k14)));
        v4f a3_ = FMA4(m3, k3, FMA4(m7, k7, FMA4(m11, k11, m15 * k15)));
        v4f ts_ = (a0_ + a1_) + (a2_ + a3_);
        float vp_ = (ts_.x + ts_.y) + (ts_.z + ts_.w);
        float d_ = vv - vp_;
        float x_ = d_ * d_;
        x_ = dppadd<0x111>(x_); x_ = dppadd<0x112>(x_);
        x_ = dppadd<0x114>(x_); x_ = dppadd<0x118>(x_);
        x_ = dppadd<0x142>(x_); x_ = dppadd<0x143>(x_);
        float e_ = __int_as_float(__builtin_amdgcn_readlane(__float_as_int(x_), 63));
        float gd_ = (sqrtf(e_) > th) ? d_ : 0.0f;
        v4f gdv = {gd_, gd_, gd_, gd_};
        m0  = FMA4(gdv, k0,  m0);  m1  = FMA4(gdv, k1,  m1);
        m2  = FMA4(gdv, k2,  m2);  m3  = FMA4(gdv, k3,  m3);
        m4  = FMA4(gdv, k4,  m4);  m5  = FMA4(gdv, k5,  m5);
        m6  = FMA4(gdv, k6,  m6);  m7  = FMA4(gdv, k7,  m7);
        m8  = FMA4(gdv, k8,  m8);  m9  = FMA4(gdv, k9,  m9);
        m10 = FMA4(gdv, k10, m10); m11 = FMA4(gdv, k11, m11);
        m12 = FMA4(gdv, k12, m12); m13 = FMA4(gdv, k13, m13);
        m14 = FMA4(gdv, k14, m14); m15 = FMA4(gdv, k15, m15);

        vv = vn; th = thn;
    }

    // ---- output head: vq = M q ; r = vq @ rp_W + rp_b ; out = r @ out_W + out_b
    const v4f* qq = (const v4f*)(qbuf + b * 64);
    v4f accq = {0.f, 0.f, 0.f, 0.f};
    accq = FMA4(m0,  qq[0],  accq); accq = FMA4(m1,  qq[1],  accq);
    accq = FMA4(m2,  qq[2],  accq); accq = FMA4(m3,  qq[3],  accq);
    accq = FMA4(m4,  qq[4],  accq); accq = FMA4(m5,  qq[5],  accq);
    accq = FMA4(m6,  qq[6],  accq); accq = FMA4(m7,  qq[7],  accq);
    accq = FMA4(m8,  qq[8],  accq); accq = FMA4(m9,  qq[9],  accq);
    accq = FMA4(m10, qq[10], accq); accq = FMA4(m11, qq[11], accq);
    accq = FMA4(m12, qq[12], accq); accq = FMA4(m13, qq[13], accq);
    accq = FMA4(m14, qq[14], accq); accq = FMA4(m15, qq[15], accq);
    float vq = (accq.x + accq.y) + (accq.z + accq.w);

    sh[lane] = vq;
    __syncthreads();
    float r = rp_b[lane];
#pragma unroll
    for (int ii = 0; ii < 64; ++ii) r = fmaf(sh[ii], rp_W[ii * 64 + lane], r);
    __syncthreads();
    sh[lane] = r;
    __syncthreads();
    float o = out_b[lane];
#pragma unroll
    for (int ii = 0; ii < 64; ++ii) o = fmaf(sh[ii], out_W[ii * 64 + lane], o);
    out[b * 64 + lane] = o;
}

// ---------------------------------------------------------------------------
// Launch. Workspace (fp32): knv[64][1024][128] (33.55 MB, t=1023 row unused) |
// vthr[64][1024] (262 KB) | qbuf[64][64]. Total ~33.9 MB.
// ---------------------------------------------------------------------------
extern "C" void kernel_launch(void* const* d_in, const int* in_sizes, int n_in,
                              void* d_out, int out_size, void* d_ws, size_t ws_size,
                              hipStream_t stream)
{
    const int*   seq   = (const int*)  d_in[0];
    const float* embed = (const float*)d_in[1];
    const float* ffW1  = (const float*)d_in[2];
    const float* ffb1  = (const float*)d_in[3];
    const float* ffW2  = (const float*)d_in[4];
    const float* ffb2  = (const float*)d_in[5];
    const float* lng   = (const float*)d_in[6];
    const float* lnb   = (const float*)d_in[7];
    const float* kpW   = (const float*)d_in[8];
    const float* vpW   = (const float*)d_in[9];
    const float* qpW   = (const float*)d_in[10];
    const float* rpW   = (const float*)d_in[11];
    const float* rpb   = (const float*)d_in[12];
    const float* outW  = (const float*)d_in[13];
    const float* outb  = (const float*)d_in[14];
    float* out = (float*)d_out;

    float* knv  = (float*)d_ws;
    float* vthr = knv  + (size_t)64 * 1024 * 128;
    float* qbuf = vthr + (size_t)64 * 1024;

    token_kernel<<<2048, 256, 0, stream>>>(seq, embed, ffW1, ffb1, ffW2, ffb2,
                                           lng, lnb, kpW, vpW, qpW,
                                           knv, vthr, qbuf);
    scan_kernel<<<64, 64, 0, stream>>>(knv, vthr, qbuf,
                                       rpW, rpb, outW, outb, out);
}